// Round 6
// baseline (375.020 us; speedup 1.0000x reference)
//
#include <hip/hip_runtime.h>
#include <math.h>

#define O_  32
#define I_  32
#define K_  13
#define N_  4096
#define IK  (I_ * K_)     // 416
#define OIK (O_ * IK)     // 13312
#define NB  4             // n's per block

typedef float f32x4 __attribute__((ext_vector_type(4)));

// R5 kernel, unchanged. Launched 3x this round as a timing experiment:
// dur_us = harness_floor + 3*T_kernel, so delta vs R5 = 2*T_kernel.
__global__ __launch_bounds__(256) void plaq_kernel(
    const float* __restrict__ x,      // (I, N)
    const float* __restrict__ W,      // (O, I, K)
    const float* __restrict__ b,      // (O,)
    const float* __restrict__ mask,   // (N, O, I, K)
    const int*   __restrict__ shifts, // (N, K)
    float* __restrict__ out)          // (O, N)
{
    __shared__ __align__(16) float g_lds[NB][IK];
    const int n0  = blockIdx.x * NB;
    const int tid = threadIdx.x;

    for (int idx = tid; idx < NB * IK; idx += 256) {
        int nl = idx / IK;
        int r  = idx - nl * IK;
        int i  = r / K_;
        int k  = r - i * K_;
        int s  = shifts[(n0 + nl) * K_ + k];
        g_lds[nl][r] = x[i * N_ + s];
    }

    const int o  = tid >> 3;
    const int s8 = tid & 7;
    const f32x4* w4 = (const f32x4*)(W + o * IK);
    f32x4 w[13];
#pragma unroll
    for (int m = 0; m < 13; ++m) w[m] = w4[s8 + 8 * m];
    const float bo = b[o];

    __syncthreads();

    const float scale = (float)((2.0 + 2.0 * M_E) / (M_E - 1.0));

    for (int nl = 0; nl < NB; ++nl) {
        const int n = n0 + nl;
        const f32x4* m4 = (const f32x4*)(mask + (size_t)n * OIK + o * IK);
        const f32x4* g4 = (const f32x4*)(&g_lds[nl][0]);

        f32x4 wg[13];
#pragma unroll
        for (int m = 0; m < 13; ++m) wg[m] = w[m] * g4[s8 + 8 * m];

        float a0 = 0.f, a1 = 0.f, a2 = 0.f, a3 = 0.f;
#pragma unroll
        for (int m = 0; m < 13; ++m) {
            f32x4 mv = __builtin_nontemporal_load(&m4[s8 + 8 * m]);
            a0 = fmaf(mv.x, wg[m].x, a0);
            a1 = fmaf(mv.y, wg[m].y, a1);
            a2 = fmaf(mv.z, wg[m].z, a2);
            a3 = fmaf(mv.w, wg[m].w, a3);
        }
        float acc = (a0 + a1) + (a2 + a3);

        acc += __shfl_down(acc, 4);
        acc += __shfl_down(acc, 2);
        acc += __shfl_down(acc, 1);

        if (s8 == 0) {
            float y  = acc + bo;
            float sg = 1.0f / (1.0f + __expf(-y));
            out[o * N_ + n] = (sg - 0.5f) * scale;
        }
    }
}

extern "C" void kernel_launch(void* const* d_in, const int* in_sizes, int n_in,
                              void* d_out, int out_size, void* d_ws, size_t ws_size,
                              hipStream_t stream) {
    const float* x      = (const float*)d_in[0];
    const float* Wconv  = (const float*)d_in[1];
    const float* bconv  = (const float*)d_in[2];
    const float* mask   = (const float*)d_in[3];
    const int*   shifts = (const int*)d_in[4];
    float* out = (float*)d_out;

    // 3 identical launches: timing experiment to isolate T_kernel.
    plaq_kernel<<<N_ / NB, 256, 0, stream>>>(x, Wconv, bconv, mask, shifts, out);
    plaq_kernel<<<N_ / NB, 256, 0, stream>>>(x, Wconv, bconv, mask, shifts, out);
    plaq_kernel<<<N_ / NB, 256, 0, stream>>>(x, Wconv, bconv, mask, shifts, out);
}

// Round 7
// 295.251 us; speedup vs baseline: 1.2702x; 1.2702x over previous
//
#include <hip/hip_runtime.h>
#include <math.h>

#define O_  32
#define I_  32
#define K_  13
#define N_  4096
#define IK  (I_ * K_)     // 416
#define OIK (O_ * IK)     // 13312
#define NB  8             // n's per block -> grid 512 = exactly 2 blocks/CU, no tail

typedef float f32x4 __attribute__((ext_vector_type(4)));

// R5 structure, NB=8: one LDS gather + ONE barrier per 8 n's (425 KB of mask
// streamed per barrier), W held in registers, nontemporal mask stream,
// split accumulators. T_kernel(R5, NB=4) measured ~42 us via the 3x-launch
// experiment; this targets the tail + barrier-alignment residue.
__global__ __launch_bounds__(256) void plaq_kernel(
    const float* __restrict__ x,      // (I, N)
    const float* __restrict__ W,      // (O, I, K)
    const float* __restrict__ b,      // (O,)
    const float* __restrict__ mask,   // (N, O, I, K)
    const int*   __restrict__ shifts, // (N, K)
    float* __restrict__ out)          // (O, N)
{
    __shared__ __align__(16) float g_lds[NB][IK];
    const int n0  = blockIdx.x * NB;
    const int tid = threadIdx.x;

    // Gather g[nl][i*13+k] = x[i*N + shifts[(n0+nl)*13+k]]  (3328 elems).
    for (int idx = tid; idx < NB * IK; idx += 256) {
        int nl = idx / IK;
        int r  = idx - nl * IK;
        int i  = r / K_;
        int k  = r - i * K_;
        int s  = shifts[(n0 + nl) * K_ + k];
        g_lds[nl][r] = x[i * N_ + s];
    }

    // Hoist W into registers while the gather is in flight (independent).
    const int o  = tid >> 3;
    const int s8 = tid & 7;
    const f32x4* w4 = (const f32x4*)(W + o * IK);
    f32x4 w[13];
#pragma unroll
    for (int m = 0; m < 13; ++m) w[m] = w4[s8 + 8 * m];
    const float bo = b[o];

    __syncthreads();   // the ONLY barrier in the block

    const float scale = (float)((2.0 + 2.0 * M_E) / (M_E - 1.0));

    for (int nl = 0; nl < NB; ++nl) {
        const int n = n0 + nl;
        const f32x4* m4 = (const f32x4*)(mask + (size_t)n * OIK + o * IK);
        const f32x4* g4 = (const f32x4*)(&g_lds[nl][0]);

        // wg = W * g  (g from LDS, same-address broadcast across o-groups).
        f32x4 wg[13];
#pragma unroll
        for (int m = 0; m < 13; ++m) wg[m] = w[m] * g4[s8 + 8 * m];

        // Hot loop: one nontemporal 16B mask load + 4 FMAs per iteration.
        float a0 = 0.f, a1 = 0.f, a2 = 0.f, a3 = 0.f;
#pragma unroll
        for (int m = 0; m < 13; ++m) {
            f32x4 mv = __builtin_nontemporal_load(&m4[s8 + 8 * m]);
            a0 = fmaf(mv.x, wg[m].x, a0);
            a1 = fmaf(mv.y, wg[m].y, a1);
            a2 = fmaf(mv.z, wg[m].z, a2);
            a3 = fmaf(mv.w, wg[m].w, a3);
        }
        float acc = (a0 + a1) + (a2 + a3);

        // Reduce across the 8 lanes sharing this o (within one wave).
        acc += __shfl_down(acc, 4);
        acc += __shfl_down(acc, 2);
        acc += __shfl_down(acc, 1);

        if (s8 == 0) {
            float y  = acc + bo;
            float sg = 1.0f / (1.0f + __expf(-y));
            out[o * N_ + n] = (sg - 0.5f) * scale;
        }
    }
}

extern "C" void kernel_launch(void* const* d_in, const int* in_sizes, int n_in,
                              void* d_out, int out_size, void* d_ws, size_t ws_size,
                              hipStream_t stream) {
    const float* x      = (const float*)d_in[0];
    const float* Wconv  = (const float*)d_in[1];
    const float* bconv  = (const float*)d_in[2];
    const float* mask   = (const float*)d_in[3];
    const int*   shifts = (const int*)d_in[4];
    float* out = (float*)d_out;

    plaq_kernel<<<N_ / NB, 256, 0, stream>>>(x, Wconv, bconv, mask, shifts, out);
}

// Round 8
// 292.378 us; speedup vs baseline: 1.2827x; 1.0098x over previous
//
#include <hip/hip_runtime.h>
#include <math.h>

#define O_  32
#define I_  32
#define K_  13
#define N_  4096
#define IK  (I_ * K_)     // 416
#define OIK (O_ * IK)     // 13312
#define NB  4             // n's per block (measured best: R5, T_kernel ~42 us)

typedef float f32x4 __attribute__((ext_vector_type(4)));

// Best-measured configuration (R5). Measured via 3x-launch experiment:
// T_kernel ~42.3 us = 218.5 MB mask stream @ 5.2 TB/s (82% of achievable
// HBM ceiling). NB=8 (R7) and kernel-split (R4) variants both regressed;
// the residue vs 6.3 TB/s is the shifts-gather latency phases, inherent
// to the op. dur_us is ~85% fixed harness restore/poison traffic.
__global__ __launch_bounds__(256) void plaq_kernel(
    const float* __restrict__ x,      // (I, N)
    const float* __restrict__ W,      // (O, I, K)
    const float* __restrict__ b,      // (O,)
    const float* __restrict__ mask,   // (N, O, I, K)
    const int*   __restrict__ shifts, // (N, K)
    float* __restrict__ out)          // (O, N)
{
    __shared__ __align__(16) float g_lds[NB][IK];
    const int n0  = blockIdx.x * NB;
    const int tid = threadIdx.x;

    // Gather g[nl][i*13+k] = x[i*N + shifts[(n0+nl)*13+k]]  (1664 elems).
    for (int idx = tid; idx < NB * IK; idx += 256) {
        int nl = idx / IK;
        int r  = idx - nl * IK;
        int i  = r / K_;
        int k  = r - i * K_;
        int s  = shifts[(n0 + nl) * K_ + k];
        g_lds[nl][r] = x[i * N_ + s];
    }

    // Hoist W into registers while the gather is in flight (independent).
    const int o  = tid >> 3;
    const int s8 = tid & 7;
    const f32x4* w4 = (const f32x4*)(W + o * IK);
    f32x4 w[13];
#pragma unroll
    for (int m = 0; m < 13; ++m) w[m] = w4[s8 + 8 * m];
    const float bo = b[o];

    __syncthreads();

    const float scale = (float)((2.0 + 2.0 * M_E) / (M_E - 1.0));

    for (int nl = 0; nl < NB; ++nl) {
        const int n = n0 + nl;
        const f32x4* m4 = (const f32x4*)(mask + (size_t)n * OIK + o * IK);
        const f32x4* g4 = (const f32x4*)(&g_lds[nl][0]);

        // wg = W * g  (g from LDS, same-address broadcast across o-groups).
        f32x4 wg[13];
#pragma unroll
        for (int m = 0; m < 13; ++m) wg[m] = w[m] * g4[s8 + 8 * m];

        // Hot loop: one nontemporal 16B mask load + 4 FMAs per iteration.
        float a0 = 0.f, a1 = 0.f, a2 = 0.f, a3 = 0.f;
#pragma unroll
        for (int m = 0; m < 13; ++m) {
            f32x4 mv = __builtin_nontemporal_load(&m4[s8 + 8 * m]);
            a0 = fmaf(mv.x, wg[m].x, a0);
            a1 = fmaf(mv.y, wg[m].y, a1);
            a2 = fmaf(mv.z, wg[m].z, a2);
            a3 = fmaf(mv.w, wg[m].w, a3);
        }
        float acc = (a0 + a1) + (a2 + a3);

        // Reduce across the 8 lanes sharing this o (within one wave).
        acc += __shfl_down(acc, 4);
        acc += __shfl_down(acc, 2);
        acc += __shfl_down(acc, 1);

        if (s8 == 0) {
            float y  = acc + bo;
            float sg = 1.0f / (1.0f + __expf(-y));
            out[o * N_ + n] = (sg - 0.5f) * scale;
        }
    }
}

extern "C" void kernel_launch(void* const* d_in, const int* in_sizes, int n_in,
                              void* d_out, int out_size, void* d_ws, size_t ws_size,
                              hipStream_t stream) {
    const float* x      = (const float*)d_in[0];
    const float* Wconv  = (const float*)d_in[1];
    const float* bconv  = (const float*)d_in[2];
    const float* mask   = (const float*)d_in[3];
    const int*   shifts = (const int*)d_in[4];
    float* out = (float*)d_out;

    plaq_kernel<<<N_ / NB, 256, 0, stream>>>(x, Wconv, bconv, mask, shifts, out);
}